// Round 13
// baseline (2946.039 us; speedup 1.0000x reference)
//
#include <hip/hip_runtime.h>
#include <stdint.h>

#define TT 2560
#define BB 64
#define CC 22

typedef unsigned short ushort_t;
typedef __attribute__((ext_vector_type(4))) float floatx4;
typedef __attribute__((ext_vector_type(8))) short bf16x8;
typedef __attribute__((ext_vector_type(4))) int intx4;

__device__ __forceinline__ float bf2f(ushort_t u){
  union { uint32_t i; float f; } v; v.i = ((uint32_t)u) << 16; return v.f;
}
__device__ __forceinline__ ushort_t f2bf(float f){
  union { float f; uint32_t i; } v; v.f = f;
  uint32_t r = v.i + 0x7FFFu + ((v.i >> 16) & 1u);
  return (ushort_t)(r >> 16);
}
__device__ __forceinline__ float fsig(float x){ return 1.f/(1.f + __expf(-x)); }
__device__ __forceinline__ float ftanh(float x){ return 2.f/(1.f + __expf(-2.f*x)) - 1.f; }

// LDS-only barrier: does NOT drain vmcnt; global stores/prefetch loads stay in
// flight across the 2560-step serial loop.
__device__ __forceinline__ void ldsbar(){
  asm volatile("s_waitcnt lgkmcnt(0)\n\ts_barrier" ::: "memory");
}

// int8 dot4: acc += dot(a.4xi8, b.4xi8)  (r10-proven fast on gfx950)
__device__ __forceinline__ int dot4(int a, int b, int acc){
#if __has_builtin(__builtin_amdgcn_sdot4)
  return __builtin_amdgcn_sdot4(a, b, acc, false);
#else
  #pragma unroll
  for (int j=0;j<4;j++){
    int av = (int)(char)(a >> (8*j));
    int bv = (int)(char)(b >> (8*j));
    acc += av*bv;
  }
  return acc;
#endif
}

// ---------------- K0a: cast x [B][C][T] fp32 -> xc [B][C][T] bf16 (time-contiguous)
__global__ __launch_bounds__(256) void k_convert_x(const float* __restrict__ x, ushort_t* __restrict__ xc){
  int i4 = blockIdx.x*256 + threadIdx.x;
  if (i4 >= BB*CC*TT/4) return;
  const float4 v = ((const float4*)x)[i4];
  uint2 o;
  o.x = (uint32_t)f2bf(v.x) | ((uint32_t)f2bf(v.y) << 16);
  o.y = (uint32_t)f2bf(v.z) | ((uint32_t)f2bf(v.w) << 16);
  ((uint2*)xc)[i4] = o;
}

// ---------------- K0a2 (v10): xAf[b][t][24] f32 — x vector per timestep,
// broadcast-consumed by all lanes (c>=22 zero-padded).
__global__ __launch_bounds__(256) void k_prep_xa(const ushort_t* __restrict__ xc, float* __restrict__ xAf){
  int idx = blockIdx.x*256 + threadIdx.x;          // ((b*TT + t)*24 + c)
  if (idx >= BB*TT*24) return;
  int c = idx % 24;
  int rest = idx / 24;
  int t = rest % TT, b = rest / TT;
  float v = 0.f;
  if (c < CC) v = bf2f(xc[((size_t)b*CC + c)*TT + t]);
  xAf[idx] = v;
}

// ---------------- K0w: per-tensor absmax of the 4 recurrent weight matrices.
__global__ __launch_bounds__(256) void k_wmax(const float* __restrict__ w0f, const float* __restrict__ w0b,
                                              const float* __restrict__ w1f, const float* __restrict__ w1b,
                                              float* __restrict__ scl){
  const int b = blockIdx.x;
  const float* W = (b==0) ? w0f : (b==1) ? w0b : (b==2) ? w1f : w1b;
  const int n = (b < 2) ? 128*512 : 64*256;
  float mx = 0.f;
  for (int i = threadIdx.x; i < n; i += 256) mx = fmaxf(mx, fabsf(W[i]));
  __shared__ float red[256];
  red[threadIdx.x] = mx;
  __syncthreads();
  for (int s = 128; s > 0; s >>= 1){
    if (threadIdx.x < s) red[threadIdx.x] = fmaxf(red[threadIdx.x], red[threadIdx.x+s]);
    __syncthreads();
  }
  if (threadIdx.x == 0) scl[b] = fmaxf(red[0], 1e-8f);
}

// ---------------- K0b (v10): layer-0 weights in per-z-column order.
// W0Qd[dir][n=512][k=128] int8 (n = Keras col = g*128+u); W0Xf[dir][n=512][24] f32.
__global__ __launch_bounds__(256) void k_prep_l0(const float* __restrict__ WxF, const float* __restrict__ WhF,
                                                 const float* __restrict__ WxB, const float* __restrict__ WhB,
                                                 const float* __restrict__ scl,
                                                 char* __restrict__ W0Qd, float* __restrict__ W0Xf){
  int idx = blockIdx.x*256 + threadIdx.x;
  if (idx >= 2*512*160) return;
  int dir = idx / 81920; int r0 = idx % 81920; int n = r0 / 160; int k = r0 % 160;
  if (k < 128){
    const float* Wh = dir ? WhB : WhF;
    float sw = scl[dir];
    W0Qd[(size_t)dir*65536 + n*128 + k] = (char)(int)rintf(Wh[k*512 + n] * (127.f/sw));
  } else {
    int kx = k - 128;
    if (kx < 24){
      const float* Wx = dir ? WxB : WxF;
      W0Xf[(size_t)dir*12288 + n*24 + kx] = (kx < CC) ? Wx[kx*512 + n] : 0.f;
    }
  }
}

// ---------------- K0c: W1Q[dir][n=256][k=64] int8 (n = Keras col = g*64+u)
__global__ __launch_bounds__(256) void k_prep_l1(const float* __restrict__ WhF, const float* __restrict__ WhB,
                                                 const float* __restrict__ scl,
                                                 char* __restrict__ W1Q){
  int idx = blockIdx.x*256 + threadIdx.x;
  if (idx >= 2*256*64) return;
  int dir = idx >> 14; int r = idx & 16383; int n = r >> 6; int k = r & 63;
  const float* Wh = dir ? WhB : WhF;
  float sw = scl[2+dir];
  W1Q[(size_t)dir*16384 + n*64 + k] = (char)(int)rintf(Wh[k*256 + n] * (127.f/sw));
}

// ---------------- K0d: WT[dir][n=256][k=256] = Wx1[k][n]  (for xz1 gemm)
__global__ __launch_bounds__(256) void k_prep_wxT(const float* __restrict__ Wf, const float* __restrict__ Wb,
                                                  ushort_t* __restrict__ WT){
  int idx = blockIdx.x*256 + threadIdx.x;
  int dir = idx >> 16; int r = idx & 65535; int n = r >> 8; int k = r & 255;
  const float* W = dir ? Wb : Wf;
  WT[idx] = f2bf(W[k*256 + n]);
}

// ---------------- K1: layer-0 scan v10: dot4, no MFMA. One chain/WG, 128 WGs,
// 8 waves (2/SIMD for latency interleave — r10 lesson). Each lane owns z-col
// n=g*128+u (r8 mapping, swizzle-combine unchanged); h via 8 broadcast
// ds_read_b128; 32 sdot4 (4 parallel chains) replace 12 MFMAs (482 -> ~64
// issue cyc/SIMD, only useful MACs); x-part = 22 register fmas on prefetched
// f32 x (replaces 4 bf16 MFMAs + tile-select cndmasks).
__global__ __launch_bounds__(512, 1) void k_lstm0m(
  const float* __restrict__ xAf, const char* __restrict__ W0Qd,
  const float* __restrict__ W0Xf, const float* __restrict__ scl,
  const float* __restrict__ bF, const float* __restrict__ bB,
  ushort_t* __restrict__ h0seq)                     // [B][T][256]: fwd 0..127, bwd 128..255
{
  const int dir = blockIdx.x & 1, b = blockIdx.x >> 1;    // b 0..63
  const int tid = threadIdx.x;
  const int wv = tid >> 6, lane = tid & 63, m = lane & 15, q = lane >> 4;
  const int g  = m & 3;                                   // gate of this lane
  const int u  = wv*16 + q*4 + (m >> 2);                  // unit of this lane
  const int n  = g*128 + u;                               // z column
  const float* bi = dir ? bB : bF;
  const float sclc = scl[dir] * (1.f/16129.f);            // sw/(127*127)
  const float em = (g==2) ? -2.f : -1.f;                  // tanh = 2*sig(2x)-1
  const float ym = (g==2) ?  2.f :  1.f;
  const float ya = (g==2) ? -1.f :  0.f;
  const float bzl = bi[n];

  __shared__ __align__(16) char AbufC[2][128];            // h int8, double-buffered

  // weights: Wh column (32 dwords i8) + Wx column (22 f32)
  intx4 Wd[8];
  {
    const char* Wq = W0Qd + (size_t)dir*65536 + (size_t)n*128;
    #pragma unroll
    for (int c=0; c<8; c++) Wd[c] = ((const intx4*)Wq)[c];
  }
  float Wxr[22];
  {
    const float* wxp = W0Xf + (size_t)dir*12288 + (size_t)n*24;
    #pragma unroll
    for (int c=0; c<22; c++) Wxr[c] = wxp[c];
  }

  if (tid < 64) ((uint32_t*)AbufC)[tid] = 0u;             // zero both buffers

  // x prefetch: 2 slots x 24 f32 (broadcast — all lanes same address)
  const float* xap = xAf + (size_t)b*TT*24;
  float4 xv0[6], xv1[6];
  {
    int t0 = dir ? (TT-1) : 0;
    int t1 = dir ? (TT-2) : 1;
    #pragma unroll
    for (int c=0; c<6; c++){
      xv0[c] = ((const float4*)(xap + (size_t)t0*24))[c];
      xv1[c] = ((const float4*)(xap + (size_t)t1*24))[c];
    }
  }
  const float* xpp = xap + (size_t)(dir ? (TT-3) : 2)*24;
  const int xstep = dir ? -24 : 24;   // floats per step
  __syncthreads();

  float cst = 0.f;
  const int t00 = dir ? TT-1 : 0;
  ushort_t* hp = h0seq + ((size_t)b*TT + t00)*256 + dir*128 + u;
  const int hstep = dir ? -256 : 256;

  for (int i = 0; i < TT/4; ++i){
    #pragma unroll
    for (int p = 0; p < 4; ++p){
      const int s = i*4 + p;
      const int cur = s & 1, nxt = cur ^ 1;

      // broadcast-read full h vector (8 x b128, same addr across lanes)
      intx4 H[8];
      {
        const intx4* hv = (const intx4*)&AbufC[cur][0];
        #pragma unroll
        for (int c=0; c<8; c++) H[c] = hv[c];
      }

      // x-dot (register-only; runs under the ds_read shadow). slot = p&1.
      float zx = bzl;
      {
        const float* xf = (p & 1) ? (const float*)xv1 : (const float*)xv0;
        #pragma unroll
        for (int c=0; c<22; c++) zx = fmaf(xf[c], Wxr[c], zx);
      }
      // reload this slot for step s+2 (stepped pointer; over-reads harmless)
      {
        float4* xs = (p & 1) ? xv1 : xv0;
        #pragma unroll
        for (int c=0; c<6; c++) xs[c] = ((const float4*)xpp)[c];
        xpp += xstep;
      }

      // h-dot: 32 sdot4 in 4 parallel chains
      int e0 = 0, e1 = 0, e2 = 0, e3 = 0;
      #pragma unroll
      for (int c=0; c<8; c++){
        e0 = dot4(H[c][0], Wd[c][0], e0);
        e1 = dot4(H[c][1], Wd[c][1], e1);
        e2 = dot4(H[c][2], Wd[c][2], e2);
        e3 = dot4(H[c][3], Wd[c][3], e3);
      }
      int acc = (e0 + e1) + (e2 + e3);

      {
        float z = (float)acc*sclc + zx;
        float e = __expf(z * em);
        float y = 1.f/(1.f + e);
        float act = ym*y + ya;               // sigmoid or tanh (exact)

        int ai = __float_as_int(act);
        float sf = __int_as_float(__builtin_amdgcn_ds_swizzle(ai, 0x041F)); // ^1 -> f
        float sg = __int_as_float(__builtin_amdgcn_ds_swizzle(ai, 0x081F)); // ^2 -> g^
        float so = __int_as_float(__builtin_amdgcn_ds_swizzle(ai, 0x0C1F)); // ^3 -> o

        float cc = sf*cst + act*sg;          // f*c + i*g^   (valid in g==0 lanes)
        cst = cc;
        float hl = so*ftanh(cc);             // o*tanh(c)
        if (g == 0){
          AbufC[nxt][u] = (char)(int)rintf(hl * 127.f);
          *hp = f2bf(hl);                    // fire-and-forget bf16 h
        }
        hp += hstep;
      }
      ldsbar();
    }
  }
}

// ---------------- K2: xz1R[dir][b][t][u(64)][g(4)] = bf16( h0seq[bt][:256] @ Wx1[dir] )
__global__ __launch_bounds__(512) void k_xz1_gemm(const ushort_t* __restrict__ h0seq,
                                                  const ushort_t* __restrict__ WxT,
                                                  ushort_t* __restrict__ xz1)
{
  const int mb  = blockIdx.x;
  const int dir = blockIdx.y;
  const ushort_t* W   = WxT + (size_t)dir*256*256;
  ushort_t*       out = xz1 + (size_t)dir*BB*TT*256;
  const int wave = threadIdx.x >> 6;
  const int lane = threadIdx.x & 63;
  const int mw = wave & 3;
  const int nw = wave >> 2;
  const int m_ = lane & 15;
  const int q_ = lane >> 4;

  floatx4 acc[2][8];
  #pragma unroll
  for (int a=0;a<2;a++)
    #pragma unroll
    for (int n=0;n<8;n++) acc[a][n] = (floatx4)0.f;

  const size_t Abase = ((size_t)mb*128 + mw*32 + m_)*256 + q_*8;
  const size_t Bbase = ((size_t)nw*128 + m_)*256 + q_*8;

  for (int kc = 0; kc < 256; kc += 32){
    bf16x8 afr[2];
    #pragma unroll
    for (int mt=0;mt<2;mt++)
      afr[mt] = *(const bf16x8*)(h0seq + Abase + (size_t)mt*16*256 + kc);
    #pragma unroll
    for (int nt=0;nt<8;nt++){
      bf16x8 bfr = *(const bf16x8*)(W + Bbase + (size_t)nt*16*256 + kc);
      #pragma unroll
      for (int mt=0;mt<2;mt++)
        acc[mt][nt] = __builtin_amdgcn_mfma_f32_16x16x32_bf16(afr[mt], bfr, acc[mt][nt], 0,0,0);
    }
  }
  #pragma unroll
  for (int mt=0;mt<2;mt++)
    #pragma unroll
    for (int r=0;r<4;r++){
      size_t bt = (size_t)mb*128 + mw*32 + mt*16 + q_*4 + r;
      ushort_t* rowp = out + bt*256;
      #pragma unroll
      for (int wvz=0; wvz<4; wvz++){
        uint32_t lo = f2bf(acc[mt][wvz][r]);
        uint32_t hi = f2bf(acc[mt][wvz+4][r]);
        *(uint32_t*)(rowp + (wvz*16+m_)*4 + 2*nw) = lo | (hi << 16);
      }
    }
}

// ---------------- K3: layer-1 scan v10: dot4 on the v8 skeleton. One chain/WG,
// 128 WGs, 4 waves; lane owns z-col n=g*64+u; h via 4 broadcast ds_read_b128;
// 16 sdot4 replace 4 MFMAs + select; swizzle gate-combine; ONE barrier.
__global__ __launch_bounds__(256, 1) void k_lstm1m(
  const ushort_t* __restrict__ xz1R,                // [dir][b][t][u][g] bf16
  const char* __restrict__ W1Q,                     // [dir][n=256][k=64] int8
  const float* __restrict__ scl,
  const float* __restrict__ bF, const float* __restrict__ bB,
  float* __restrict__ h1last)                       // [B][128]: fwd 0..63, bwd 64..127
{
  const int dir = blockIdx.x & 1, b = blockIdx.x >> 1;    // b 0..63
  const int tid = threadIdx.x;
  const int wv = tid >> 6, lane = tid & 63, m = lane & 15, q = lane >> 4;
  const int g = m & 3;                                    // gate of this lane
  const int u = wv*16 + q*4 + (m >> 2);                   // unit of this lane
  const int n = g*64 + u;                                 // z column
  const float* bi = dir ? bB : bF;
  const float sclc = scl[2+dir] * (1.f/16129.f);
  const float em = (g==2) ? -2.f : -1.f;
  const float ym = (g==2) ?  2.f :  1.f;
  const float ya = (g==2) ? -1.f :  0.f;
  const float bzl = bi[n];

  __shared__ __align__(16) char HbufC[2][64];             // h int8, double-buffered

  intx4 Wd[4];
  {
    const char* Wq = W1Q + (size_t)dir*16384 + (size_t)n*64;
    #pragma unroll
    for (int c=0; c<4; c++) Wd[c] = ((const intx4*)Wq)[c];
  }

  if (tid < 32) ((uint32_t*)HbufC)[tid] = 0u;             // zero both buffers

  const ushort_t* xzr = xz1R + ((size_t)dir*BB + b)*TT*256 + (size_t)(u*4 + g);
  ushort_t pz[4];
  #pragma unroll
  for (int j=0; j<4; j++){
    int tj = dir ? (TT-1-j) : j;
    pz[j] = xzr[(size_t)tj*256];
  }
  const ushort_t* xpp = xzr + (size_t)(dir ? (TT-5) : 4)*256;
  const int zstep = dir ? -256 : 256;      // ushorts per step
  __syncthreads();

  float cst = 0.f, hl = 0.f;

  for (int i = 0; i < TT/4; ++i){
    #pragma unroll
    for (int p = 0; p < 4; ++p){
      const int s = i*4 + p;
      const int cur = s & 1, nxt = cur ^ 1;

      intx4 H[4];
      {
        const intx4* hv = (const intx4*)&HbufC[cur][0];
        #pragma unroll
        for (int c=0; c<4; c++) H[c] = hv[c];
      }

      // hoisted xz+bias partial under the ds_read shadow, + stepped reload
      float w = bzl + bf2f(pz[p]);
      pz[p] = *xpp;
      xpp += zstep;

      int e0 = 0, e1 = 0, e2 = 0, e3 = 0;
      #pragma unroll
      for (int c=0; c<4; c++){
        e0 = dot4(H[c][0], Wd[c][0], e0);
        e1 = dot4(H[c][1], Wd[c][1], e1);
        e2 = dot4(H[c][2], Wd[c][2], e2);
        e3 = dot4(H[c][3], Wd[c][3], e3);
      }
      int acc = (e0 + e1) + (e2 + e3);

      {
        float z = (float)acc*sclc + w;
        float e = __expf(z * em);
        float y = 1.f/(1.f + e);
        float act = ym*y + ya;               // sigmoid or tanh (exact)

        int ai = __float_as_int(act);
        float sf = __int_as_float(__builtin_amdgcn_ds_swizzle(ai, 0x041F)); // ^1 -> f
        float sg = __int_as_float(__builtin_amdgcn_ds_swizzle(ai, 0x081F)); // ^2 -> g^
        float so = __int_as_float(__builtin_amdgcn_ds_swizzle(ai, 0x0C1F)); // ^3 -> o

        float cc = sf*cst + act*sg;          // valid in g==0 lanes
        cst = cc;
        hl = so*ftanh(cc);
        if (g == 0) HbufC[nxt][u] = (char)(int)rintf(hl * 127.f);
      }
      ldsbar();
    }
  }
  if (g == 0) h1last[(size_t)b*128 + dir*64 + u] = hl;
}

// ---------------- K4: dense head
__global__ __launch_bounds__(128) void k_head(
  const float* __restrict__ h1last,
  const float* __restrict__ d0W, const float* __restrict__ d0b,
  const float* __restrict__ d1W, const float* __restrict__ d1b,
  const float* __restrict__ oW,  const float* __restrict__ ob,
  float* __restrict__ outp)
{
  const int b = blockIdx.x;
  const int j = threadIdx.x;
  __shared__ float v0[128], v1[128];
  v0[j] = h1last[b*128 + j];
  __syncthreads();
  float acc = d0b[j];
  #pragma unroll
  for (int k=0;k<128;k++) acc += v0[k]*d0W[k*128 + j];
  v1[j] = fmaxf(acc, 0.f);
  __syncthreads();
  if (j < 64){
    float a2 = d1b[j];
    #pragma unroll
    for (int k=0;k<128;k++) a2 += v1[k]*d1W[k*64 + j];
    float p = fmaxf(a2, 0.f) * oW[j];
    #pragma unroll
    for (int off=32; off>0; off>>=1) p += __shfl_down(p, off, 64);
    if (j == 0) outp[b] = 1.f/(1.f + __expf(-(p + ob[0])));
  }
}

extern "C" void kernel_launch(void* const* d_in, const int* in_sizes, int n_in,
                              void* d_out, int out_size, void* d_ws, size_t ws_size,
                              hipStream_t stream)
{
  const float* x     = (const float*)d_in[0];
  const float* l0fWx = (const float*)d_in[1];
  const float* l0fWh = (const float*)d_in[2];
  const float* l0fb  = (const float*)d_in[3];
  const float* l0bWx = (const float*)d_in[4];
  const float* l0bWh = (const float*)d_in[5];
  const float* l0bb  = (const float*)d_in[6];
  const float* l1fWx = (const float*)d_in[7];
  const float* l1fWh = (const float*)d_in[8];
  const float* l1fb  = (const float*)d_in[9];
  const float* l1bWx = (const float*)d_in[10];
  const float* l1bWh = (const float*)d_in[11];
  const float* l1bb  = (const float*)d_in[12];
  const float* d0W = (const float*)d_in[13];
  const float* d0b = (const float*)d_in[14];
  const float* d1W = (const float*)d_in[15];
  const float* d1b = (const float*)d_in[16];
  const float* oW  = (const float*)d_in[17];
  const float* ob  = (const float*)d_in[18];
  float* outp = (float*)d_out;

  char* ws = (char*)d_ws;
  const size_t OFF_XT  = 0;                        // xc: 7,208,960 (slot 7,864,320)
  const size_t OFF_SCL = 7208960ull;               // 16 B (xc slot slack)
  const size_t OFF_H0  = OFF_XT  + 7864320ull;     // 83,886,080
  const size_t OFF_XZ  = OFF_H0  + 83886080ull;    // 167,772,160 (xz1R; xAf overlaps head)
  const size_t OFF_XA  = OFF_XZ;                   // xAf: 15,728,640 (dead before xz1 written)
  const size_t OFF_WT  = OFF_XZ  + 167772160ull;   // 262,144
  const size_t OFF_B0  = OFF_WT  + 262144ull;      // slot 327,680: W0Qd 131,072 + W0Xf 98,304
  const size_t OFF_B0X = OFF_B0  + 131072ull;
  const size_t OFF_B1  = OFF_B0  + 327680ull;      // slot 65,536: W1Q 32,768
  const size_t OFF_H1  = OFF_B1  + 65536ull;       // 32,768

  ushort_t* xc  = (ushort_t*)(ws + OFF_XT);
  float*    sclp= (float*)(ws + OFF_SCL);
  ushort_t* h0  = (ushort_t*)(ws + OFF_H0);
  ushort_t* xz1 = (ushort_t*)(ws + OFF_XZ);
  float*    xAf = (float*)(ws + OFF_XA);
  ushort_t* WT  = (ushort_t*)(ws + OFF_WT);
  char*     W0Qd= (char*)(ws + OFF_B0);
  float*    W0Xf= (float*)(ws + OFF_B0X);
  char*     W1Q = (char*)(ws + OFF_B1);
  float*    h1l = (float*)(ws + OFF_H1);

  hipLaunchKernelGGL(k_convert_x,   dim3(3520), dim3(256), 0, stream, x, xc);
  hipLaunchKernelGGL(k_prep_xa,     dim3(15360), dim3(256), 0, stream, xc, xAf);
  hipLaunchKernelGGL(k_wmax,        dim3(4),    dim3(256), 0, stream, l0fWh, l0bWh, l1fWh, l1bWh, sclp);
  hipLaunchKernelGGL(k_prep_l0,     dim3(640),  dim3(256), 0, stream, l0fWx, l0fWh, l0bWx, l0bWh, sclp, W0Qd, W0Xf);
  hipLaunchKernelGGL(k_prep_l1,     dim3(128),  dim3(256), 0, stream, l1fWh, l1bWh, sclp, W1Q);
  hipLaunchKernelGGL(k_prep_wxT,    dim3(512),  dim3(256), 0, stream, l1fWx, l1bWx, WT);
  hipLaunchKernelGGL(k_lstm0m,      dim3(128),  dim3(512), 0, stream, xAf, W0Qd, W0Xf, sclp, l0fb, l0bb, h0);
  hipLaunchKernelGGL(k_xz1_gemm,    dim3(1280,2), dim3(512), 0, stream, h0, WT, xz1);
  hipLaunchKernelGGL(k_lstm1m,      dim3(128),  dim3(256), 0, stream, xz1, W1Q, sclp, l1fb, l1bb, h1l);
  hipLaunchKernelGGL(k_head,        dim3(64),   dim3(128), 0, stream,
                     h1l, d0W, d0b, d1W, d1b, oW, ob, outp);
}

// Round 14
// 2811.736 us; speedup vs baseline: 1.0478x; 1.0478x over previous
//
#include <hip/hip_runtime.h>
#include <stdint.h>

#define TT 2560
#define BB 64
#define CC 22

typedef unsigned short ushort_t;
typedef __attribute__((ext_vector_type(4))) float floatx4;
typedef __attribute__((ext_vector_type(8))) short bf16x8;
typedef __attribute__((ext_vector_type(4))) int intx4;

__device__ __forceinline__ float bf2f(ushort_t u){
  union { uint32_t i; float f; } v; v.i = ((uint32_t)u) << 16; return v.f;
}
__device__ __forceinline__ ushort_t f2bf(float f){
  union { float f; uint32_t i; } v; v.f = f;
  uint32_t r = v.i + 0x7FFFu + ((v.i >> 16) & 1u);
  return (ushort_t)(r >> 16);
}
__device__ __forceinline__ float fsig(float x){ return 1.f/(1.f + __expf(-x)); }
__device__ __forceinline__ float ftanh(float x){ return 2.f/(1.f + __expf(-2.f*x)) - 1.f; }

// LDS-only barrier: drains lgkmcnt (LDS + SMEM) but NOT vmcnt — global vector
// loads/stores stay in flight across the 2560-step serial loop.
__device__ __forceinline__ void ldsbar(){
  asm volatile("s_waitcnt lgkmcnt(0)\n\ts_barrier" ::: "memory");
}

// int8 dot4: acc += dot(a.4xi8, b.4xi8)
__device__ __forceinline__ int dot4(int a, int b, int acc){
#if __has_builtin(__builtin_amdgcn_sdot4)
  return __builtin_amdgcn_sdot4(a, b, acc, false);
#else
  #pragma unroll
  for (int j=0;j<4;j++){
    int av = (int)(char)(a >> (8*j));
    int bv = (int)(char)(b >> (8*j));
    acc += av*bv;
  }
  return acc;
#endif
}

#define FMA4(acc, a, b) do{ \
  (acc).x = fmaf((a).x, (b).x, (acc).x); \
  (acc).y = fmaf((a).y, (b).y, (acc).y); \
  (acc).z = fmaf((a).z, (b).z, (acc).z); \
  (acc).w = fmaf((a).w, (b).w, (acc).w); }while(0)

// ---------------- K0a: cast x [B][C][T] fp32 -> xc [B][C][T] bf16 (time-contiguous)
__global__ __launch_bounds__(256) void k_convert_x(const float* __restrict__ x, ushort_t* __restrict__ xc){
  int i4 = blockIdx.x*256 + threadIdx.x;
  if (i4 >= BB*CC*TT/4) return;
  const float4 v = ((const float4*)x)[i4];
  uint2 o;
  o.x = (uint32_t)f2bf(v.x) | ((uint32_t)f2bf(v.y) << 16);
  o.y = (uint32_t)f2bf(v.z) | ((uint32_t)f2bf(v.w) << 16);
  ((uint2*)xc)[i4] = o;
}

// ---------------- K0a2 (v11): xAf[b][t][rep=4][24] f32 — x replicated 4x so the
// scan's load address is LANE-VARIANT (q picks a replica) -> guaranteed vector
// loads (vmcnt domain; ldsbar's lgkmcnt(0) cannot drain them). r13 lesson: the
// uniform-address version was scalarized to s_load (lgkmcnt) and serialized.
__global__ __launch_bounds__(256) void k_prep_xa(const ushort_t* __restrict__ xc, float* __restrict__ xAf){
  int idx = blockIdx.x*256 + threadIdx.x;          // (((b*TT + t)*4 + q)*24 + c)
  if (idx >= BB*TT*4*24) return;
  int c = idx % 24;
  int rest = idx / 24;
  int t = (rest >> 2) % TT, b = (rest >> 2) / TT;
  float v = 0.f;
  if (c < CC) v = bf2f(xc[((size_t)b*CC + c)*TT + t]);
  xAf[idx] = v;
}

// ---------------- K0w: per-tensor absmax of the 4 recurrent weight matrices.
__global__ __launch_bounds__(256) void k_wmax(const float* __restrict__ w0f, const float* __restrict__ w0b,
                                              const float* __restrict__ w1f, const float* __restrict__ w1b,
                                              float* __restrict__ scl){
  const int b = blockIdx.x;
  const float* W = (b==0) ? w0f : (b==1) ? w0b : (b==2) ? w1f : w1b;
  const int n = (b < 2) ? 128*512 : 64*256;
  float mx = 0.f;
  for (int i = threadIdx.x; i < n; i += 256) mx = fmaxf(mx, fabsf(W[i]));
  __shared__ float red[256];
  red[threadIdx.x] = mx;
  __syncthreads();
  for (int s = 128; s > 0; s >>= 1){
    if (threadIdx.x < s) red[threadIdx.x] = fmaxf(red[threadIdx.x], red[threadIdx.x+s]);
    __syncthreads();
  }
  if (threadIdx.x == 0) scl[b] = fmaxf(red[0], 1e-8f);
}

// ---------------- K0b: layer-0 weights in per-z-column order.
// W0Qd[dir][n=512][k=128] int8 (n = Keras col = g*128+u); W0Xf[dir][n=512][24] f32.
__global__ __launch_bounds__(256) void k_prep_l0(const float* __restrict__ WxF, const float* __restrict__ WhF,
                                                 const float* __restrict__ WxB, const float* __restrict__ WhB,
                                                 const float* __restrict__ scl,
                                                 char* __restrict__ W0Qd, float* __restrict__ W0Xf){
  int idx = blockIdx.x*256 + threadIdx.x;
  if (idx >= 2*512*160) return;
  int dir = idx / 81920; int r0 = idx % 81920; int n = r0 / 160; int k = r0 % 160;
  if (k < 128){
    const float* Wh = dir ? WhB : WhF;
    float sw = scl[dir];
    W0Qd[(size_t)dir*65536 + n*128 + k] = (char)(int)rintf(Wh[k*512 + n] * (127.f/sw));
  } else {
    int kx = k - 128;
    if (kx < 24){
      const float* Wx = dir ? WxB : WxF;
      W0Xf[(size_t)dir*12288 + n*24 + kx] = (kx < CC) ? Wx[kx*512 + n] : 0.f;
    }
  }
}

// ---------------- K0c: W1Q[dir][n=256][k=64] int8 (n = Keras col = g*64+u)
__global__ __launch_bounds__(256) void k_prep_l1(const float* __restrict__ WhF, const float* __restrict__ WhB,
                                                 const float* __restrict__ scl,
                                                 char* __restrict__ W1Q){
  int idx = blockIdx.x*256 + threadIdx.x;
  if (idx >= 2*256*64) return;
  int dir = idx >> 14; int r = idx & 16383; int n = r >> 6; int k = r & 63;
  const float* Wh = dir ? WhB : WhF;
  float sw = scl[2+dir];
  W1Q[(size_t)dir*16384 + n*64 + k] = (char)(int)rintf(Wh[k*256 + n] * (127.f/sw));
}

// ---------------- K0d: WT[dir][n=256][k=256] = Wx1[k][n]  (for xz1 gemm)
__global__ __launch_bounds__(256) void k_prep_wxT(const float* __restrict__ Wf, const float* __restrict__ Wb,
                                                  ushort_t* __restrict__ WT){
  int idx = blockIdx.x*256 + threadIdx.x;
  int dir = idx >> 16; int r = idx & 65535; int n = r >> 8; int k = r & 255;
  const float* W = dir ? Wb : Wf;
  WT[idx] = f2bf(W[k*256 + n]);
}

// ---------------- K1: layer-0 scan v11: dot4 with codegen-safe register state.
// All hot per-lane state in NAMED variables (no arrays, no pointer-selects —
// r13's scratch/remat trigger). x loads vector (lane-variant replica address).
__global__ __launch_bounds__(512, 1) void k_lstm0m(
  const float* __restrict__ xAf, const char* __restrict__ W0Qd,
  const float* __restrict__ W0Xf, const float* __restrict__ scl,
  const float* __restrict__ bF, const float* __restrict__ bB,
  ushort_t* __restrict__ h0seq)                     // [B][T][256]: fwd 0..127, bwd 128..255
{
  const int dir = blockIdx.x & 1, b = blockIdx.x >> 1;    // b 0..63
  const int tid = threadIdx.x;
  const int wv = tid >> 6, lane = tid & 63, m = lane & 15, q = lane >> 4;
  const int g  = m & 3;                                   // gate of this lane
  const int u  = wv*16 + q*4 + (m >> 2);                  // unit of this lane
  const int n  = g*128 + u;                               // z column
  const float* bi = dir ? bB : bF;
  const float sclc = scl[dir] * (1.f/16129.f);            // sw/(127*127)
  const float em = (g==2) ? -2.f : -1.f;                  // tanh = 2*sig(2x)-1
  const float ym = (g==2) ?  2.f :  1.f;
  const float ya = (g==2) ? -1.f :  0.f;
  const float bzl = bi[n];

  __shared__ __align__(16) char AbufC[2][128];            // h int8, double-buffered

  // Wh column (8 named intx4) + Wx column (6 named float4; pads are 0)
  intx4 Wd0, Wd1, Wd2, Wd3, Wd4, Wd5, Wd6, Wd7;
  {
    const intx4* Wq = (const intx4*)(W0Qd + (size_t)dir*65536 + (size_t)n*128);
    Wd0=Wq[0]; Wd1=Wq[1]; Wd2=Wq[2]; Wd3=Wq[3]; Wd4=Wq[4]; Wd5=Wq[5]; Wd6=Wq[6]; Wd7=Wq[7];
  }
  float4 wx0, wx1, wx2, wx3, wx4, wx5;
  {
    const float4* wxp = (const float4*)(W0Xf + (size_t)dir*12288 + (size_t)n*24);
    wx0=wxp[0]; wx1=wxp[1]; wx2=wxp[2]; wx3=wxp[3]; wx4=wxp[4]; wx5=wxp[5];
  }

  if (tid < 64) ((uint32_t*)AbufC)[tid] = 0u;             // zero both buffers

  // x prefetch: 2 slots x 6 named float4; replica address depends on q -> vector
  const float* xap = xAf + ((size_t)b*TT*4 + (size_t)q)*24;
  float4 xa0,xa1,xa2,xa3,xa4,xa5, xb0,xb1,xb2,xb3,xb4,xb5;
  {
    const float4* p0 = (const float4*)(xap + (size_t)(dir ? (TT-1) : 0)*96);
    const float4* p1 = (const float4*)(xap + (size_t)(dir ? (TT-2) : 1)*96);
    xa0=p0[0]; xa1=p0[1]; xa2=p0[2]; xa3=p0[3]; xa4=p0[4]; xa5=p0[5];
    xb0=p1[0]; xb1=p1[1]; xb2=p1[2]; xb3=p1[3]; xb4=p1[4]; xb5=p1[5];
  }
  const float* xpp = xap + (size_t)(dir ? (TT-3) : 2)*96;
  const int xstep = dir ? -96 : 96;   // floats per t-step
  __syncthreads();

  float cst = 0.f;
  const int t00 = dir ? TT-1 : 0;
  ushort_t* hp = h0seq + ((size_t)b*TT + t00)*256 + dir*128 + u;
  const int hstep = dir ? -256 : 256;

  for (int i = 0; i < TT/4; ++i){
    #pragma unroll
    for (int p = 0; p < 4; ++p){
      const int s = i*4 + p;
      const int cur = s & 1, nxt = cur ^ 1;

      // broadcast-read full h vector (8 x b128, same addr across lanes)
      intx4 H0,H1,H2,H3,H4,H5,H6,H7;
      {
        const intx4* hv = (const intx4*)&AbufC[cur][0];
        H0=hv[0]; H1=hv[1]; H2=hv[2]; H3=hv[3]; H4=hv[4]; H5=hv[5]; H6=hv[6]; H7=hv[7];
      }

      // x-dot on slot (p&1), then reload that slot for step s+2 (vector loads)
      float zx;
      if ((p & 1) == 0){
        float4 t_ = {0.f,0.f,0.f,0.f};
        FMA4(t_, xa0, wx0); FMA4(t_, xa1, wx1); FMA4(t_, xa2, wx2);
        FMA4(t_, xa3, wx3); FMA4(t_, xa4, wx4); FMA4(t_, xa5, wx5);
        zx = bzl + (t_.x + t_.y) + (t_.z + t_.w);
        const float4* pl = (const float4*)xpp;
        xa0=pl[0]; xa1=pl[1]; xa2=pl[2]; xa3=pl[3]; xa4=pl[4]; xa5=pl[5];
      } else {
        float4 t_ = {0.f,0.f,0.f,0.f};
        FMA4(t_, xb0, wx0); FMA4(t_, xb1, wx1); FMA4(t_, xb2, wx2);
        FMA4(t_, xb3, wx3); FMA4(t_, xb4, wx4); FMA4(t_, xb5, wx5);
        zx = bzl + (t_.x + t_.y) + (t_.z + t_.w);
        const float4* pl = (const float4*)xpp;
        xb0=pl[0]; xb1=pl[1]; xb2=pl[2]; xb3=pl[3]; xb4=pl[4]; xb5=pl[5];
      }
      xpp += xstep;

      // h-dot: 32 sdot4 in 4 parallel chains
      int e0 = 0, e1 = 0, e2 = 0, e3 = 0;
      e0 = dot4(H0[0], Wd0[0], e0); e1 = dot4(H0[1], Wd0[1], e1);
      e2 = dot4(H0[2], Wd0[2], e2); e3 = dot4(H0[3], Wd0[3], e3);
      e0 = dot4(H1[0], Wd1[0], e0); e1 = dot4(H1[1], Wd1[1], e1);
      e2 = dot4(H1[2], Wd1[2], e2); e3 = dot4(H1[3], Wd1[3], e3);
      e0 = dot4(H2[0], Wd2[0], e0); e1 = dot4(H2[1], Wd2[1], e1);
      e2 = dot4(H2[2], Wd2[2], e2); e3 = dot4(H2[3], Wd2[3], e3);
      e0 = dot4(H3[0], Wd3[0], e0); e1 = dot4(H3[1], Wd3[1], e1);
      e2 = dot4(H3[2], Wd3[2], e2); e3 = dot4(H3[3], Wd3[3], e3);
      e0 = dot4(H4[0], Wd4[0], e0); e1 = dot4(H4[1], Wd4[1], e1);
      e2 = dot4(H4[2], Wd4[2], e2); e3 = dot4(H4[3], Wd4[3], e3);
      e0 = dot4(H5[0], Wd5[0], e0); e1 = dot4(H5[1], Wd5[1], e1);
      e2 = dot4(H5[2], Wd5[2], e2); e3 = dot4(H5[3], Wd5[3], e3);
      e0 = dot4(H6[0], Wd6[0], e0); e1 = dot4(H6[1], Wd6[1], e1);
      e2 = dot4(H6[2], Wd6[2], e2); e3 = dot4(H6[3], Wd6[3], e3);
      e0 = dot4(H7[0], Wd7[0], e0); e1 = dot4(H7[1], Wd7[1], e1);
      e2 = dot4(H7[2], Wd7[2], e2); e3 = dot4(H7[3], Wd7[3], e3);
      int acc = (e0 + e1) + (e2 + e3);

      {
        float z = (float)acc*sclc + zx;
        float e = __expf(z * em);
        float y = 1.f/(1.f + e);
        float act = ym*y + ya;               // sigmoid or tanh (exact)

        int ai = __float_as_int(act);
        float sf = __int_as_float(__builtin_amdgcn_ds_swizzle(ai, 0x041F)); // ^1 -> f
        float sg = __int_as_float(__builtin_amdgcn_ds_swizzle(ai, 0x081F)); // ^2 -> g^
        float so = __int_as_float(__builtin_amdgcn_ds_swizzle(ai, 0x0C1F)); // ^3 -> o

        float cc = sf*cst + act*sg;          // f*c + i*g^   (valid in g==0 lanes)
        cst = cc;
        float hl = so*ftanh(cc);             // o*tanh(c)
        if (g == 0){
          AbufC[nxt][u] = (char)(int)rintf(hl * 127.f);
          *hp = f2bf(hl);                    // fire-and-forget bf16 h
        }
        hp += hstep;
      }
      ldsbar();
    }
  }
}

// ---------------- K2: xz1R[dir][b][t][u(64)][g(4)] = bf16( h0seq[bt][:256] @ Wx1[dir] )
__global__ __launch_bounds__(512) void k_xz1_gemm(const ushort_t* __restrict__ h0seq,
                                                  const ushort_t* __restrict__ WxT,
                                                  ushort_t* __restrict__ xz1)
{
  const int mb  = blockIdx.x;
  const int dir = blockIdx.y;
  const ushort_t* W   = WxT + (size_t)dir*256*256;
  ushort_t*       out = xz1 + (size_t)dir*BB*TT*256;
  const int wave = threadIdx.x >> 6;
  const int lane = threadIdx.x & 63;
  const int mw = wave & 3;
  const int nw = wave >> 2;
  const int m_ = lane & 15;
  const int q_ = lane >> 4;

  floatx4 acc[2][8];
  #pragma unroll
  for (int a=0;a<2;a++)
    #pragma unroll
    for (int n=0;n<8;n++) acc[a][n] = (floatx4)0.f;

  const size_t Abase = ((size_t)mb*128 + mw*32 + m_)*256 + q_*8;
  const size_t Bbase = ((size_t)nw*128 + m_)*256 + q_*8;

  for (int kc = 0; kc < 256; kc += 32){
    bf16x8 afr[2];
    #pragma unroll
    for (int mt=0;mt<2;mt++)
      afr[mt] = *(const bf16x8*)(h0seq + Abase + (size_t)mt*16*256 + kc);
    #pragma unroll
    for (int nt=0;nt<8;nt++){
      bf16x8 bfr = *(const bf16x8*)(W + Bbase + (size_t)nt*16*256 + kc);
      #pragma unroll
      for (int mt=0;mt<2;mt++)
        acc[mt][nt] = __builtin_amdgcn_mfma_f32_16x16x32_bf16(afr[mt], bfr, acc[mt][nt], 0,0,0);
    }
  }
  #pragma unroll
  for (int mt=0;mt<2;mt++)
    #pragma unroll
    for (int r=0;r<4;r++){
      size_t bt = (size_t)mb*128 + mw*32 + mt*16 + q_*4 + r;
      ushort_t* rowp = out + bt*256;
      #pragma unroll
      for (int wvz=0; wvz<4; wvz++){
        uint32_t lo = f2bf(acc[mt][wvz][r]);
        uint32_t hi = f2bf(acc[mt][wvz+4][r]);
        *(uint32_t*)(rowp + (wvz*16+m_)*4 + 2*nw) = lo | (hi << 16);
      }
    }
}

// ---------------- K3: layer-1 scan v11: dot4 on the v8 skeleton, codegen-safe
// named registers (r13: VGPR=28 proved spill/remat). 128 WGs x 4 waves.
__global__ __launch_bounds__(256, 1) void k_lstm1m(
  const ushort_t* __restrict__ xz1R,                // [dir][b][t][u][g] bf16
  const char* __restrict__ W1Q,                     // [dir][n=256][k=64] int8
  const float* __restrict__ scl,
  const float* __restrict__ bF, const float* __restrict__ bB,
  float* __restrict__ h1last)                       // [B][128]: fwd 0..63, bwd 64..127
{
  const int dir = blockIdx.x & 1, b = blockIdx.x >> 1;    // b 0..63
  const int tid = threadIdx.x;
  const int wv = tid >> 6, lane = tid & 63, m = lane & 15, q = lane >> 4;
  const int g = m & 3;                                    // gate of this lane
  const int u = wv*16 + q*4 + (m >> 2);                   // unit of this lane
  const int n = g*64 + u;                                 // z column
  const float* bi = dir ? bB : bF;
  const float sclc = scl[2+dir] * (1.f/16129.f);
  const float em = (g==2) ? -2.f : -1.f;
  const float ym = (g==2) ?  2.f :  1.f;
  const float ya = (g==2) ? -1.f :  0.f;
  const float bzl = bi[n];

  __shared__ __align__(16) char HbufC[2][64];             // h int8, double-buffered

  intx4 Wd0, Wd1, Wd2, Wd3;
  {
    const intx4* Wq = (const intx4*)(W1Q + (size_t)dir*16384 + (size_t)n*64);
    Wd0=Wq[0]; Wd1=Wq[1]; Wd2=Wq[2]; Wd3=Wq[3];
  }

  if (tid < 32) ((uint32_t*)HbufC)[tid] = 0u;             // zero both buffers

  const ushort_t* xzr = xz1R + ((size_t)dir*BB + b)*TT*256 + (size_t)(u*4 + g);
  ushort_t pz0, pz1, pz2, pz3;
  {
    int tj0 = dir ? (TT-1) : 0, tj1 = dir ? (TT-2) : 1;
    int tj2 = dir ? (TT-3) : 2, tj3 = dir ? (TT-4) : 3;
    pz0 = xzr[(size_t)tj0*256]; pz1 = xzr[(size_t)tj1*256];
    pz2 = xzr[(size_t)tj2*256]; pz3 = xzr[(size_t)tj3*256];
  }
  const ushort_t* xpp = xzr + (size_t)(dir ? (TT-5) : 4)*256;
  const int zstep = dir ? -256 : 256;      // ushorts per step
  __syncthreads();

  float cst = 0.f, hl = 0.f;

  for (int i = 0; i < TT/4; ++i){
    #pragma unroll
    for (int p = 0; p < 4; ++p){
      const int s = i*4 + p;
      const int cur = s & 1, nxt = cur ^ 1;

      intx4 H0,H1,H2,H3;
      {
        const intx4* hv = (const intx4*)&HbufC[cur][0];
        H0=hv[0]; H1=hv[1]; H2=hv[2]; H3=hv[3];
      }

      // hoisted xz+bias partial under the ds_read shadow, + stepped reload
      float w;
      if      (p == 0){ w = bzl + bf2f(pz0); pz0 = *xpp; }
      else if (p == 1){ w = bzl + bf2f(pz1); pz1 = *xpp; }
      else if (p == 2){ w = bzl + bf2f(pz2); pz2 = *xpp; }
      else            { w = bzl + bf2f(pz3); pz3 = *xpp; }
      xpp += zstep;

      int e0 = 0, e1 = 0, e2 = 0, e3 = 0;
      e0 = dot4(H0[0], Wd0[0], e0); e1 = dot4(H0[1], Wd0[1], e1);
      e2 = dot4(H0[2], Wd0[2], e2); e3 = dot4(H0[3], Wd0[3], e3);
      e0 = dot4(H1[0], Wd1[0], e0); e1 = dot4(H1[1], Wd1[1], e1);
      e2 = dot4(H1[2], Wd1[2], e2); e3 = dot4(H1[3], Wd1[3], e3);
      e0 = dot4(H2[0], Wd2[0], e0); e1 = dot4(H2[1], Wd2[1], e1);
      e2 = dot4(H2[2], Wd2[2], e2); e3 = dot4(H2[3], Wd2[3], e3);
      e0 = dot4(H3[0], Wd3[0], e0); e1 = dot4(H3[1], Wd3[1], e1);
      e2 = dot4(H3[2], Wd3[2], e2); e3 = dot4(H3[3], Wd3[3], e3);
      int acc = (e0 + e1) + (e2 + e3);

      {
        float z = (float)acc*sclc + w;
        float e = __expf(z * em);
        float y = 1.f/(1.f + e);
        float act = ym*y + ya;               // sigmoid or tanh (exact)

        int ai = __float_as_int(act);
        float sf = __int_as_float(__builtin_amdgcn_ds_swizzle(ai, 0x041F)); // ^1 -> f
        float sg = __int_as_float(__builtin_amdgcn_ds_swizzle(ai, 0x081F)); // ^2 -> g^
        float so = __int_as_float(__builtin_amdgcn_ds_swizzle(ai, 0x0C1F)); // ^3 -> o

        float cc = sf*cst + act*sg;          // valid in g==0 lanes
        cst = cc;
        hl = so*ftanh(cc);
        if (g == 0) HbufC[nxt][u] = (char)(int)rintf(hl * 127.f);
      }
      ldsbar();
    }
  }
  if (g == 0) h1last[(size_t)b*128 + dir*64 + u] = hl;
}

// ---------------- K4: dense head
__global__ __launch_bounds__(128) void k_head(
  const float* __restrict__ h1last,
  const float* __restrict__ d0W, const float* __restrict__ d0b,
  const float* __restrict__ d1W, const float* __restrict__ d1b,
  const float* __restrict__ oW,  const float* __restrict__ ob,
  float* __restrict__ outp)
{
  const int b = blockIdx.x;
  const int j = threadIdx.x;
  __shared__ float v0[128], v1[128];
  v0[j] = h1last[b*128 + j];
  __syncthreads();
  float acc = d0b[j];
  #pragma unroll
  for (int k=0;k<128;k++) acc += v0[k]*d0W[k*128 + j];
  v1[j] = fmaxf(acc, 0.f);
  __syncthreads();
  if (j < 64){
    float a2 = d1b[j];
    #pragma unroll
    for (int k=0;k<128;k++) a2 += v1[k]*d1W[k*64 + j];
    float p = fmaxf(a2, 0.f) * oW[j];
    #pragma unroll
    for (int off=32; off>0; off>>=1) p += __shfl_down(p, off, 64);
    if (j == 0) outp[b] = 1.f/(1.f + __expf(-(p + ob[0])));
  }
}

extern "C" void kernel_launch(void* const* d_in, const int* in_sizes, int n_in,
                              void* d_out, int out_size, void* d_ws, size_t ws_size,
                              hipStream_t stream)
{
  const float* x     = (const float*)d_in[0];
  const float* l0fWx = (const float*)d_in[1];
  const float* l0fWh = (const float*)d_in[2];
  const float* l0fb  = (const float*)d_in[3];
  const float* l0bWx = (const float*)d_in[4];
  const float* l0bWh = (const float*)d_in[5];
  const float* l0bb  = (const float*)d_in[6];
  const float* l1fWx = (const float*)d_in[7];
  const float* l1fWh = (const float*)d_in[8];
  const float* l1fb  = (const float*)d_in[9];
  const float* l1bWx = (const float*)d_in[10];
  const float* l1bWh = (const float*)d_in[11];
  const float* l1bb  = (const float*)d_in[12];
  const float* d0W = (const float*)d_in[13];
  const float* d0b = (const float*)d_in[14];
  const float* d1W = (const float*)d_in[15];
  const float* d1b = (const float*)d_in[16];
  const float* oW  = (const float*)d_in[17];
  const float* ob  = (const float*)d_in[18];
  float* outp = (float*)d_out;

  char* ws = (char*)d_ws;
  const size_t OFF_XT  = 0;                        // xc: 7,208,960 (slot 7,864,320)
  const size_t OFF_SCL = 7208960ull;               // 16 B (xc slot slack)
  const size_t OFF_H0  = OFF_XT  + 7864320ull;     // 83,886,080
  const size_t OFF_XZ  = OFF_H0  + 83886080ull;    // 167,772,160 (xz1R; xAf overlaps head)
  const size_t OFF_XA  = OFF_XZ;                   // xAf: 62,914,560 (dead before xz1 written)
  const size_t OFF_WT  = OFF_XZ  + 167772160ull;   // 262,144
  const size_t OFF_B0  = OFF_WT  + 262144ull;      // slot 327,680: W0Qd 131,072 + W0Xf 98,304
  const size_t OFF_B0X = OFF_B0  + 131072ull;
  const size_t OFF_B1  = OFF_B0  + 327680ull;      // slot 65,536: W1Q 32,768
  const size_t OFF_H1  = OFF_B1  + 65536ull;       // 32,768

  ushort_t* xc  = (ushort_t*)(ws + OFF_XT);
  float*    sclp= (float*)(ws + OFF_SCL);
  ushort_t* h0  = (ushort_t*)(ws + OFF_H0);
  ushort_t* xz1 = (ushort_t*)(ws + OFF_XZ);
  float*    xAf = (float*)(ws + OFF_XA);
  ushort_t* WT  = (ushort_t*)(ws + OFF_WT);
  char*     W0Qd= (char*)(ws + OFF_B0);
  float*    W0Xf= (float*)(ws + OFF_B0X);
  char*     W1Q = (char*)(ws + OFF_B1);
  float*    h1l = (float*)(ws + OFF_H1);

  hipLaunchKernelGGL(k_convert_x,   dim3(3520), dim3(256), 0, stream, x, xc);
  hipLaunchKernelGGL(k_prep_xa,     dim3(61440), dim3(256), 0, stream, xc, xAf);
  hipLaunchKernelGGL(k_wmax,        dim3(4),    dim3(256), 0, stream, l0fWh, l0bWh, l1fWh, l1bWh, sclp);
  hipLaunchKernelGGL(k_prep_l0,     dim3(640),  dim3(256), 0, stream, l0fWx, l0fWh, l0bWx, l0bWh, sclp, W0Qd, W0Xf);
  hipLaunchKernelGGL(k_prep_l1,     dim3(128),  dim3(256), 0, stream, l1fWh, l1bWh, sclp, W1Q);
  hipLaunchKernelGGL(k_prep_wxT,    dim3(512),  dim3(256), 0, stream, l1fWx, l1bWx, WT);
  hipLaunchKernelGGL(k_lstm0m,      dim3(128),  dim3(512), 0, stream, xAf, W0Qd, W0Xf, sclp, l0fb, l0bb, h0);
  hipLaunchKernelGGL(k_xz1_gemm,    dim3(1280,2), dim3(512), 0, stream, h0, WT, xz1);
  hipLaunchKernelGGL(k_lstm1m,      dim3(128),  dim3(256), 0, stream, xz1, W1Q, sclp, l1fb, l1bb, h1l);
  hipLaunchKernelGGL(k_head,        dim3(64),   dim3(128), 0, stream,
                     h1l, d0W, d0b, d1W, d1b, oW, ob, outp);
}

// Round 15
// 2105.481 us; speedup vs baseline: 1.3992x; 1.3354x over previous
//
#include <hip/hip_runtime.h>
#include <stdint.h>

#define TT 2560
#define BB 64
#define CC 22

typedef unsigned short ushort_t;
typedef __attribute__((ext_vector_type(4))) float floatx4;
typedef __attribute__((ext_vector_type(8))) short bf16x8;
typedef __attribute__((ext_vector_type(4))) int intx4;

__device__ __forceinline__ float bf2f(ushort_t u){
  union { uint32_t i; float f; } v; v.i = ((uint32_t)u) << 16; return v.f;
}
__device__ __forceinline__ ushort_t f2bf(float f){
  union { float f; uint32_t i; } v; v.f = f;
  uint32_t r = v.i + 0x7FFFu + ((v.i >> 16) & 1u);
  return (ushort_t)(r >> 16);
}
__device__ __forceinline__ float fsig(float x){ return 1.f/(1.f + __expf(-x)); }
__device__ __forceinline__ float ftanh(float x){ return 2.f/(1.f + __expf(-2.f*x)) - 1.f; }

// LDS-only barrier: does NOT drain vmcnt; global stores/prefetch loads stay in
// flight across the 2560-step serial loop.
__device__ __forceinline__ void ldsbar(){
  asm volatile("s_waitcnt lgkmcnt(0)\n\ts_barrier" ::: "memory");
}

// ---------------- K0a: cast x [B][C][T] fp32 -> xc [B][C][T] bf16 (time-contiguous)
__global__ __launch_bounds__(256) void k_convert_x(const float* __restrict__ x, ushort_t* __restrict__ xc){
  int i4 = blockIdx.x*256 + threadIdx.x;
  if (i4 >= BB*CC*TT/4) return;
  const float4 v = ((const float4*)x)[i4];
  uint2 o;
  o.x = (uint32_t)f2bf(v.x) | ((uint32_t)f2bf(v.y) << 16);
  o.y = (uint32_t)f2bf(v.z) | ((uint32_t)f2bf(v.w) << 16);
  ((uint2*)xc)[i4] = o;
}

// ---------------- K0a2: pack x into q-only A-fragment order (v7).
// xA[b][t][q][8]: lane (m,q) holds x channels q*8..q*8+7 (bf16, 0-padded >=22);
// value independent of m (A rows are replicas).
__global__ __launch_bounds__(256) void k_prep_xa(const ushort_t* __restrict__ xc, ushort_t* __restrict__ xA){
  int idx = blockIdx.x*256 + threadIdx.x;          // ((b*TT + t)*4 + q)
  if (idx >= BB*TT*4) return;
  int q = idx & 3;
  int rest = idx >> 2;
  int t = rest % TT, b = rest / TT;
  ushort_t v[8];
  #pragma unroll
  for (int j=0;j<8;j++){
    int c = q*8 + j;
    v[j] = (c < CC) ? xc[((size_t)b*CC + c)*TT + t] : (ushort_t)0;
  }
  *(uint4*)(xA + (size_t)idx*8) = *(const uint4*)v;
}

// ---------------- K0w: per-tensor absmax of the 4 recurrent weight matrices.
__global__ __launch_bounds__(256) void k_wmax(const float* __restrict__ w0f, const float* __restrict__ w0b,
                                              const float* __restrict__ w1f, const float* __restrict__ w1b,
                                              float* __restrict__ scl){
  const int b = blockIdx.x;
  const float* W = (b==0) ? w0f : (b==1) ? w0b : (b==2) ? w1f : w1b;
  const int n = (b < 2) ? 128*512 : 64*256;
  float mx = 0.f;
  for (int i = threadIdx.x; i < n; i += 256) mx = fmaxf(mx, fabsf(W[i]));
  __shared__ float red[256];
  red[threadIdx.x] = mx;
  __syncthreads();
  for (int s = 128; s > 0; s >>= 1){
    if (threadIdx.x < s) red[threadIdx.x] = fmaxf(red[threadIdx.x], red[threadIdx.x+s]);
    __syncthreads();
  }
  if (threadIdx.x == 0) scl[b] = fmaxf(red[0], 1e-8f);
}

// ---------------- K0b: layer-0 weights, v7 PERMUTED n-tile layout.
// n = g*128 + u (g=gate, u=unit); u = wv*16 + qq*4 + r.
// Dest row = (qq*8 + wv)*16 + (r*4 + g): the MFMA for lane-quarter qq of wave wv
// delivers z[n] at column m = r*4+g.
__global__ __launch_bounds__(256) void k_prep_l0(const float* __restrict__ WxF, const float* __restrict__ WhF,
                                                 const float* __restrict__ WxB, const float* __restrict__ WhB,
                                                 const float* __restrict__ scl,
                                                 char* __restrict__ W0Q, ushort_t* __restrict__ B0X){
  int idx = blockIdx.x*256 + threadIdx.x;
  if (idx >= 2*512*160) return;
  int dir = idx / 81920; int r0 = idx % 81920; int n = r0 / 160; int k = r0 % 160;
  int g = n >> 7, u = n & 127;
  int wv = u >> 4, qq = (u >> 2) & 3, r = u & 3;
  int row = (qq*8 + wv)*16 + (r*4 + g);
  if (k < 128){
    const float* Wh = dir ? WhB : WhF;
    float sw = scl[dir];
    W0Q[(size_t)dir*65536 + row*128 + k] = (char)(int)rintf(Wh[k*512 + n] * (127.f/sw));
  } else {
    const float* Wx = dir ? WxB : WxF;
    int kx = k - 128;
    float v = (kx < CC) ? Wx[kx*512 + n] : 0.f;
    B0X[(size_t)dir*16384 + row*32 + kx] = f2bf(v);
  }
}

// ---------------- K0c: layer-1 weights, v8 PERMUTED n-tile layout (same scheme).
// n = g*64 + u; u = wv*16 + qq*4 + r (wv 0..3). Dest row = (qq*4 + wv)*16 + (r*4 + g).
__global__ __launch_bounds__(256) void k_prep_l1(const float* __restrict__ WhF, const float* __restrict__ WhB,
                                                 const float* __restrict__ scl,
                                                 char* __restrict__ W1Q){
  int idx = blockIdx.x*256 + threadIdx.x;
  if (idx >= 2*256*64) return;
  int dir = idx >> 14; int r0 = idx & 16383; int n = r0 >> 6; int k = r0 & 63;
  int g = n >> 6, u = n & 63;
  int wv = u >> 4, qq = (u >> 2) & 3, r = u & 3;
  int row = (qq*4 + wv)*16 + (r*4 + g);
  const float* Wh = dir ? WhB : WhF;
  float sw = scl[2+dir];
  W1Q[(size_t)dir*16384 + row*64 + k] = (char)(int)rintf(Wh[k*256 + n] * (127.f/sw));
}

// ---------------- K0d: WT[dir][n=256][k=256] = Wx1[k][n]  (for xz1 gemm)
__global__ __launch_bounds__(256) void k_prep_wxT(const float* __restrict__ Wf, const float* __restrict__ Wb,
                                                  ushort_t* __restrict__ WT){
  int idx = blockIdx.x*256 + threadIdx.x;
  int dir = idx >> 16; int r = idx & 65535; int n = r >> 8; int k = r & 255;
  const float* W = dir ? Wb : Wf;
  WT[idx] = f2bf(W[k*256 + n]);
}

// ---------------- K1: layer-0 scan v7 (r8/r9-proven): one chain/WG, 128 WGs,
// 8 waves; each lane owns one z value (gate g=m&3, unit u=wv*16+q*4+(m>>2));
// i8 MFMA recurrence + bf16 MFMA x-part; ds_swizzle gate-combine.
// r14 lesson: MFMA-parallel-with-VALU beats fewer-total-VALU dot4 (1016 vs 1710).
__global__ __launch_bounds__(512, 1) void k_lstm0m(
  const ushort_t* __restrict__ xA, const char* __restrict__ W0Q,
  const ushort_t* __restrict__ B0X, const float* __restrict__ scl,
  const float* __restrict__ bF, const float* __restrict__ bB,
  ushort_t* __restrict__ h0seq)                     // [B][T][256]: fwd 0..127, bwd 128..255
{
  const int dir = blockIdx.x & 1, b = blockIdx.x >> 1;    // b 0..63
  const int tid = threadIdx.x;
  const int wv = tid >> 6, lane = tid & 63, m = lane & 15, q = lane >> 4;
  const int g  = m & 3;                                   // gate of this lane
  const int u  = wv*16 + q*4 + (m >> 2);                  // unit of this lane
  const float* bi = dir ? bB : bF;
  const float sclc = scl[dir] * (1.f/16129.f);            // sw/(127*127)
  // activation constants: gate 2 is tanh = 2*sigmoid(2x)-1 (exact: x2 is lossless)
  const float em = (g==2) ? -2.f : -1.f;
  const float ym = (g==2) ?  2.f :  1.f;
  const float ya = (g==2) ? -1.f :  0.f;
  const float bzl = bi[g*128 + u];

  __shared__ __align__(16) char AbufC[2][128];            // h int8, double-buffered

  // B fragments: tile qt (lane-quarter) -> rows (qt*8+wv)*16 + m
  bf16x8 Bfx[4];
  intx4  BfQ[4][2];
  {
    const ushort_t* Bx = B0X + (size_t)dir*16384;
    const char*     Bq = W0Q + (size_t)dir*65536;
    #pragma unroll
    for (int qt=0; qt<4; qt++){
      int nrow = (qt*8 + wv)*16 + m;
      Bfx[qt] = *(const bf16x8*)(Bx + (size_t)nrow*32 + q*8);
      #pragma unroll
      for (int kt=0; kt<2; kt++)
        BfQ[qt][kt] = *(const intx4*)(Bq + (size_t)nrow*128 + kt*64 + q*16);
    }
  }

  if (tid < 64) ((uint32_t*)AbufC)[tid] = 0u;             // zero both buffers

  // x fragment stream: value depends only on q (16-lane broadcast loads)
  const ushort_t* xap = xA + ((size_t)b*TT*4 + q)*8;
  uint4 px[4];
  #pragma unroll
  for (int j=0; j<4; j++){
    int tj = dir ? (TT-1-j) : j;
    px[j] = *(const uint4*)(xap + (size_t)tj*32);
  }
  const ushort_t* xpp = xap + (size_t)(dir ? (TT-5) : 4)*32;
  const int xstep = dir ? -32 : 32;   // ushorts per step
  __syncthreads();

  const floatx4 z4 = {0.f,0.f,0.f,0.f};
  const intx4  zi = {0,0,0,0};
  float cst = 0.f;
  const int t00 = dir ? TT-1 : 0;
  ushort_t* hp = h0seq + ((size_t)b*TT + t00)*256 + dir*128 + u;
  const int hstep = dir ? -256 : 256;

  for (int i = 0; i < TT/4; ++i){
    #pragma unroll
    for (int p = 0; p < 4; ++p){
      const int s = i*4 + p;
      const int cur = s & 1, nxt = cur ^ 1;

      const char* ar = &AbufC[cur][0];
      intx4 AfQ0 = *(const intx4*)(ar + q*16);
      intx4 AfQ1 = *(const intx4*)(ar + 64 + q*16);
      bf16x8 Ax = *(const bf16x8*)&px[p];

      // 4 independent tile-chains (x bf16 first: register operands cover ds_read)
      floatx4 ax0 = __builtin_amdgcn_mfma_f32_16x16x32_bf16(Ax, Bfx[0], z4, 0,0,0);
      floatx4 ax1 = __builtin_amdgcn_mfma_f32_16x16x32_bf16(Ax, Bfx[1], z4, 0,0,0);
      floatx4 ax2 = __builtin_amdgcn_mfma_f32_16x16x32_bf16(Ax, Bfx[2], z4, 0,0,0);
      floatx4 ax3 = __builtin_amdgcn_mfma_f32_16x16x32_bf16(Ax, Bfx[3], z4, 0,0,0);

      intx4 aq0 = __builtin_amdgcn_mfma_i32_16x16x64_i8(AfQ0, BfQ[0][0], zi, 0,0,0);
      intx4 aq1 = __builtin_amdgcn_mfma_i32_16x16x64_i8(AfQ0, BfQ[1][0], zi, 0,0,0);
      intx4 aq2 = __builtin_amdgcn_mfma_i32_16x16x64_i8(AfQ0, BfQ[2][0], zi, 0,0,0);
      intx4 aq3 = __builtin_amdgcn_mfma_i32_16x16x64_i8(AfQ0, BfQ[3][0], zi, 0,0,0);
      aq0 = __builtin_amdgcn_mfma_i32_16x16x64_i8(AfQ1, BfQ[0][1], aq0, 0,0,0);
      aq1 = __builtin_amdgcn_mfma_i32_16x16x64_i8(AfQ1, BfQ[1][1], aq1, 0,0,0);
      aq2 = __builtin_amdgcn_mfma_i32_16x16x64_i8(AfQ1, BfQ[2][1], aq2, 0,0,0);
      aq3 = __builtin_amdgcn_mfma_i32_16x16x64_i8(AfQ1, BfQ[3][1], aq3, 0,0,0);

      // px reload for step s+4
      px[p] = *(const uint4*)xpp;
      xpp += xstep;

      // select this lane's tile (qt = q): 3 cndmask per operand
      float axs = (q < 2) ? ((q == 0) ? ax0[0] : ax1[0])
                          : ((q == 2) ? ax2[0] : ax3[0]);
      int   aqs = (q < 2) ? ((q == 0) ? aq0[0] : aq1[0])
                          : ((q == 2) ? aq2[0] : aq3[0]);

      {
        float z = (float)aqs*sclc + axs + bzl;
        float e = __expf(z * em);
        float y = 1.f/(1.f + e);
        float act = ym*y + ya;               // sigmoid or tanh (exact)

        int ai = __float_as_int(act);
        float sf = __int_as_float(__builtin_amdgcn_ds_swizzle(ai, 0x041F)); // ^1 -> f
        float sg = __int_as_float(__builtin_amdgcn_ds_swizzle(ai, 0x081F)); // ^2 -> g^
        float so = __int_as_float(__builtin_amdgcn_ds_swizzle(ai, 0x0C1F)); // ^3 -> o

        float cc = sf*cst + act*sg;          // f*c + i*g^   (valid in g==0 lanes)
        cst = cc;
        float hl = so*ftanh(cc);             // o*tanh(c)
        if (g == 0){
          AbufC[nxt][u] = (char)(int)rintf(hl * 127.f);
          *hp = f2bf(hl);                    // fire-and-forget bf16 h
        }
        hp += hstep;
      }
      ldsbar();
    }
  }
}

// ---------------- K2: xz1R[dir][b][t][u(64)][g(4)] = bf16( h0seq[bt][:256] @ Wx1[dir] )
__global__ __launch_bounds__(512) void k_xz1_gemm(const ushort_t* __restrict__ h0seq,
                                                  const ushort_t* __restrict__ WxT,
                                                  ushort_t* __restrict__ xz1)
{
  const int mb  = blockIdx.x;
  const int dir = blockIdx.y;
  const ushort_t* W   = WxT + (size_t)dir*256*256;
  ushort_t*       out = xz1 + (size_t)dir*BB*TT*256;
  const int wave = threadIdx.x >> 6;
  const int lane = threadIdx.x & 63;
  const int mw = wave & 3;
  const int nw = wave >> 2;
  const int m_ = lane & 15;
  const int q_ = lane >> 4;

  floatx4 acc[2][8];
  #pragma unroll
  for (int a=0;a<2;a++)
    #pragma unroll
    for (int n=0;n<8;n++) acc[a][n] = (floatx4)0.f;

  const size_t Abase = ((size_t)mb*128 + mw*32 + m_)*256 + q_*8;
  const size_t Bbase = ((size_t)nw*128 + m_)*256 + q_*8;

  for (int kc = 0; kc < 256; kc += 32){
    bf16x8 afr[2];
    #pragma unroll
    for (int mt=0;mt<2;mt++)
      afr[mt] = *(const bf16x8*)(h0seq + Abase + (size_t)mt*16*256 + kc);
    #pragma unroll
    for (int nt=0;nt<8;nt++){
      bf16x8 bfr = *(const bf16x8*)(W + Bbase + (size_t)nt*16*256 + kc);
      #pragma unroll
      for (int mt=0;mt<2;mt++)
        acc[mt][nt] = __builtin_amdgcn_mfma_f32_16x16x32_bf16(afr[mt], bfr, acc[mt][nt], 0,0,0);
    }
  }
  #pragma unroll
  for (int mt=0;mt<2;mt++)
    #pragma unroll
    for (int r=0;r<4;r++){
      size_t bt = (size_t)mb*128 + mw*32 + mt*16 + q_*4 + r;
      ushort_t* rowp = out + bt*256;
      #pragma unroll
      for (int wvz=0; wvz<4; wvz++){
        uint32_t lo = f2bf(acc[mt][wvz][r]);
        uint32_t hi = f2bf(acc[mt][wvz+4][r]);
        *(uint32_t*)(rowp + (wvz*16+m_)*4 + 2*nw) = lo | (hi << 16);
      }
    }
}

// ---------------- K3: layer-1 scan v8 (r9-proven): one chain per WG, 128 WGs,
// 4 waves; each lane owns ONE z value; per-wave MFMA = 4 independent K=64 i8;
// gates combined via ds_swizzle xor1/2/3; xz prefetch one coalesced ushort.
__global__ __launch_bounds__(256, 1) void k_lstm1m(
  const ushort_t* __restrict__ xz1R,                // [dir][b][t][u][g] bf16
  const char* __restrict__ W1Q,                     // permuted [dir][row][k=64] int8
  const float* __restrict__ scl,
  const float* __restrict__ bF, const float* __restrict__ bB,
  float* __restrict__ h1last)                       // [B][128]: fwd 0..63, bwd 64..127
{
  const int dir = blockIdx.x & 1, b = blockIdx.x >> 1;    // b 0..63
  const int tid = threadIdx.x;
  const int wv = tid >> 6, lane = tid & 63, m = lane & 15, q = lane >> 4;
  const int g = m & 3;                                    // gate of this lane
  const int u = wv*16 + q*4 + (m >> 2);                   // unit of this lane
  const float* bi = dir ? bB : bF;
  const float sclc = scl[2+dir] * (1.f/16129.f);
  const float em = (g==2) ? -2.f : -1.f;
  const float ym = (g==2) ?  2.f :  1.f;
  const float ya = (g==2) ? -1.f :  0.f;
  const float bzl = bi[g*64 + u];

  __shared__ __align__(16) char HbufC[2][64];             // h int8, double-buffered

  intx4 BfQ[4];                           // tile qt -> row (qt*4+wv)*16 + m
  {
    const char* Bq = W1Q + (size_t)dir*16384;
    #pragma unroll
    for (int qt=0; qt<4; qt++)
      BfQ[qt] = *(const intx4*)(Bq + (size_t)((qt*4 + wv)*16 + m)*64 + q*16);
  }

  if (tid < 32) ((uint32_t*)HbufC)[tid] = 0u;             // zero both buffers

  const ushort_t* xzr = xz1R + ((size_t)dir*BB + b)*TT*256 + (size_t)(u*4 + g);
  ushort_t pz[4];
  #pragma unroll
  for (int j=0; j<4; j++){
    int tj = dir ? (TT-1-j) : j;
    pz[j] = xzr[(size_t)tj*256];
  }
  const ushort_t* xpp = xzr + (size_t)(dir ? (TT-5) : 4)*256;
  const int zstep = dir ? -256 : 256;      // ushorts per step
  __syncthreads();

  const intx4 zi = {0,0,0,0};
  float cst = 0.f, hl = 0.f;

  for (int i = 0; i < TT/4; ++i){
    #pragma unroll
    for (int p = 0; p < 4; ++p){
      const int s = i*4 + p;
      const int cur = s & 1, nxt = cur ^ 1;

      intx4 AfQ = *(const intx4*)(&HbufC[cur][0] + q*16);

      // hoisted xz+bias partial under the ds_read shadow, + stepped reload
      float w = bzl + bf2f(pz[p]);
      pz[p] = *xpp;
      xpp += zstep;

      // 4 independent K=64 i8 MFMAs: all 64 n-columns this wave owns
      intx4 c0 = __builtin_amdgcn_mfma_i32_16x16x64_i8(AfQ, BfQ[0], zi, 0,0,0);
      intx4 c1 = __builtin_amdgcn_mfma_i32_16x16x64_i8(AfQ, BfQ[1], zi, 0,0,0);
      intx4 c2 = __builtin_amdgcn_mfma_i32_16x16x64_i8(AfQ, BfQ[2], zi, 0,0,0);
      intx4 c3 = __builtin_amdgcn_mfma_i32_16x16x64_i8(AfQ, BfQ[3], zi, 0,0,0);

      int aqs = (q < 2) ? ((q == 0) ? c0[0] : c1[0])
                        : ((q == 2) ? c2[0] : c3[0]);

      {
        float z = (float)aqs*sclc + w;
        float e = __expf(z * em);
        float y = 1.f/(1.f + e);
        float act = ym*y + ya;               // sigmoid or tanh (exact)

        int ai = __float_as_int(act);
        float sf = __int_as_float(__builtin_amdgcn_ds_swizzle(ai, 0x041F)); // ^1 -> f
        float sg = __int_as_float(__builtin_amdgcn_ds_swizzle(ai, 0x081F)); // ^2 -> g^
        float so = __int_as_float(__builtin_amdgcn_ds_swizzle(ai, 0x0C1F)); // ^3 -> o

        float cc = sf*cst + act*sg;          // valid in g==0 lanes
        cst = cc;
        hl = so*ftanh(cc);
        if (g == 0) HbufC[nxt][u] = (char)(int)rintf(hl * 127.f);
      }
      ldsbar();
    }
  }
  if (g == 0) h1last[(size_t)b*128 + dir*64 + u] = hl;
}

// ---------------- K4: dense head
__global__ __launch_bounds__(128) void k_head(
  const float* __restrict__ h1last,
  const float* __restrict__ d0W, const float* __restrict__ d0b,
  const float* __restrict__ d1W, const float* __restrict__ d1b,
  const float* __restrict__ oW,  const float* __restrict__ ob,
  float* __restrict__ outp)
{
  const int b = blockIdx.x;
  const int j = threadIdx.x;
  __shared__ float v0[128], v1[128];
  v0[j] = h1last[b*128 + j];
  __syncthreads();
  float acc = d0b[j];
  #pragma unroll
  for (int k=0;k<128;k++) acc += v0[k]*d0W[k*128 + j];
  v1[j] = fmaxf(acc, 0.f);
  __syncthreads();
  if (j < 64){
    float a2 = d1b[j];
    #pragma unroll
    for (int k=0;k<128;k++) a2 += v1[k]*d1W[k*64 + j];
    float p = fmaxf(a2, 0.f) * oW[j];
    #pragma unroll
    for (int off=32; off>0; off>>=1) p += __shfl_down(p, off, 64);
    if (j == 0) outp[b] = 1.f/(1.f + __expf(-(p + ob[0])));
  }
}

extern "C" void kernel_launch(void* const* d_in, const int* in_sizes, int n_in,
                              void* d_out, int out_size, void* d_ws, size_t ws_size,
                              hipStream_t stream)
{
  const float* x     = (const float*)d_in[0];
  const float* l0fWx = (const float*)d_in[1];
  const float* l0fWh = (const float*)d_in[2];
  const float* l0fb  = (const float*)d_in[3];
  const float* l0bWx = (const float*)d_in[4];
  const float* l0bWh = (const float*)d_in[5];
  const float* l0bb  = (const float*)d_in[6];
  const float* l1fWx = (const float*)d_in[7];
  const float* l1fWh = (const float*)d_in[8];
  const float* l1fb  = (const float*)d_in[9];
  const float* l1bWx = (const float*)d_in[10];
  const float* l1bWh = (const float*)d_in[11];
  const float* l1bb  = (const float*)d_in[12];
  const float* d0W = (const float*)d_in[13];
  const float* d0b = (const float*)d_in[14];
  const float* d1W = (const float*)d_in[15];
  const float* d1b = (const float*)d_in[16];
  const float* oW  = (const float*)d_in[17];
  const float* ob  = (const float*)d_in[18];
  float* outp = (float*)d_out;

  char* ws = (char*)d_ws;
  const size_t OFF_XT  = 0;                        // xc: 7,208,960 (slot 7,864,320)
  const size_t OFF_SCL = 7208960ull;               // 16 B (xc slot slack)
  const size_t OFF_H0  = OFF_XT  + 7864320ull;     // 83,886,080
  const size_t OFF_XZ  = OFF_H0  + 83886080ull;    // 167,772,160 (xz1R; xA overlaps head)
  const size_t OFF_XA  = OFF_XZ;                   // xA: 2,621,440 (dead before xz1 written)
  const size_t OFF_WT  = OFF_XZ  + 167772160ull;   // 262,144
  const size_t OFF_B0  = OFF_WT  + 262144ull;      // slot 327,680: W0Q 131,072 + B0X 65,536
  const size_t OFF_B0X = OFF_B0  + 131072ull;
  const size_t OFF_B1  = OFF_B0  + 327680ull;      // slot 65,536: W1Q 32,768
  const size_t OFF_H1  = OFF_B1  + 65536ull;       // 32,768

  ushort_t* xc  = (ushort_t*)(ws + OFF_XT);
  float*    sclp= (float*)(ws + OFF_SCL);
  ushort_t* h0  = (ushort_t*)(ws + OFF_H0);
  ushort_t* xz1 = (ushort_t*)(ws + OFF_XZ);
  ushort_t* xA  = (ushort_t*)(ws + OFF_XA);
  ushort_t* WT  = (ushort_t*)(ws + OFF_WT);
  char*     W0Q = (char*)(ws + OFF_B0);
  ushort_t* B0X = (ushort_t*)(ws + OFF_B0X);
  char*     W1Q = (char*)(ws + OFF_B1);
  float*    h1l = (float*)(ws + OFF_H1);

  hipLaunchKernelGGL(k_convert_x,   dim3(3520), dim3(256), 0, stream, x, xc);
  hipLaunchKernelGGL(k_prep_xa,     dim3(2560), dim3(256), 0, stream, xc, xA);
  hipLaunchKernelGGL(k_wmax,        dim3(4),    dim3(256), 0, stream, l0fWh, l0bWh, l1fWh, l1bWh, sclp);
  hipLaunchKernelGGL(k_prep_l0,     dim3(640),  dim3(256), 0, stream, l0fWx, l0fWh, l0bWx, l0bWh, sclp, W0Q, B0X);
  hipLaunchKernelGGL(k_prep_l1,     dim3(128),  dim3(256), 0, stream, l1fWh, l1bWh, sclp, W1Q);
  hipLaunchKernelGGL(k_prep_wxT,    dim3(512),  dim3(256), 0, stream, l1fWx, l1bWx, WT);
  hipLaunchKernelGGL(k_lstm0m,      dim3(128),  dim3(512), 0, stream, xA, W0Q, B0X, sclp, l0fb, l0bb, h0);
  hipLaunchKernelGGL(k_xz1_gemm,    dim3(1280,2), dim3(512), 0, stream, h0, WT, xz1);
  hipLaunchKernelGGL(k_lstm1m,      dim3(128),  dim3(256), 0, stream, xz1, W1Q, sclp, l1fb, l1bb, h1l);
  hipLaunchKernelGGL(k_head,        dim3(64),   dim3(128), 0, stream,
                     h1l, d0W, d0b, d1W, d1b, oW, ob, outp);
}